// Round 1
// baseline (327.341 us; speedup 1.0000x reference)
//
#include <hip/hip_runtime.h>

typedef unsigned short u16;
typedef unsigned int   u32;
typedef unsigned long long u64;
typedef __attribute__((ext_vector_type(8))) short short8;
typedef __attribute__((ext_vector_type(4))) float f32x4;

#define T_TOK 8192
#define DIM   1024
#define NEXP  8
#define NPAIR (T_TOK * 2)   // 16384 token-expert pairs
#define MAXTILES 136        // sum ceil(cnt_e/128) <= 128 + 7; 136 % 8 == 0

__device__ __forceinline__ u16 f2bf(float f) {
  u32 u = __builtin_bit_cast(u32, f);
  u32 r = (u + 0x7fffu + ((u >> 16) & 1u)) >> 16;  // RNE
  return (u16)r;
}
__device__ __forceinline__ float bf2f(u16 b) {
  return __builtin_bit_cast(float, ((u32)b) << 16);
}

__device__ __forceinline__ void gl_lds16(const u16* g, u16* l) {
  __builtin_amdgcn_global_load_lds(
      (const __attribute__((address_space(1))) u32*)g,
      (__attribute__((address_space(3))) u32*)l,
      16, 0, 0);
}

// ---------------- fused prep: cast x/W1/W2 to bf16 + pair sort ---------------
// Block 0 (launched first) runs the single-block ballot sort; blocks 1..3072
// stream the fp32->bf16 cast (1024 thr x 8 elems). The ~10us serial sort hides
// entirely under the BW-bound cast, and one launch boundary disappears.
__global__ void prep_k(const float* __restrict__ x, const float* __restrict__ W1,
                       const float* __restrict__ W2,
                       u16* __restrict__ xb, u16* __restrict__ w1b, u16* __restrict__ w2b,
                       const int* __restrict__ idx,
                       int* __restrict__ counts, int* __restrict__ offsets,
                       int* __restrict__ bucket, int* __restrict__ pos,
                       int* __restrict__ tlist, int* __restrict__ ntiles) {
  __shared__ int lc[16][NEXP];
  __shared__ int lo[16][NEXP];

  if (blockIdx.x != 0) {
    // ---- cast path: 3072 blocks x 1024 threads x 8 elems = 3 x 8388608 ----
    const int g = ((int)(blockIdx.x - 1) * 1024 + (int)threadIdx.x) * 8;
    const int region = g >> 23;                      // 8388608 elems per region
    const int i = g & 0x7fffff;
    const float* s = (region == 0) ? x : (region == 1) ? W1 : W2;
    u16* d = (region == 0) ? xb : (region == 1) ? w1b : w2b;
    f32x4 a = *(const f32x4*)(s + i);
    f32x4 b = *(const f32x4*)(s + i + 4);
    short8 o;
    o[0] = (short)f2bf(a[0]); o[1] = (short)f2bf(a[1]);
    o[2] = (short)f2bf(a[2]); o[3] = (short)f2bf(a[3]);
    o[4] = (short)f2bf(b[0]); o[5] = (short)f2bf(b[1]);
    o[6] = (short)f2bf(b[2]); o[7] = (short)f2bf(b[3]);
    *(short8*)(d + i) = o;
    return;
  }

  // ---- sort path: bucket pairs by expert, ballot-based, no atomics ----
  // Emits tlist ROUND-ROBIN over experts so tile-slot p has expert p%8,
  // enabling the expert->XCD L2-locality swizzle in the GEMM.
  const int tid  = threadIdx.x;
  const int w    = tid >> 6;
  const int lane = tid & 63;
  const u64 ltmask = (lane == 63) ? 0x7fffffffffffffffull : ((1ull << lane) - 1);

  int e_i[16];
#pragma unroll
  for (int i = 0; i < 16; ++i) e_i[i] = idx[(w * 16 + i) * 64 + lane];

  int cnt[NEXP] = {};
#pragma unroll
  for (int i = 0; i < 16; ++i) {
#pragma unroll
    for (int ex = 0; ex < NEXP; ++ex) {
      u64 m = __ballot(e_i[i] == ex);
      cnt[ex] += (int)__popcll(m);
    }
  }
  if (lane == 0) {
#pragma unroll
    for (int ex = 0; ex < NEXP; ++ex) lc[w][ex] = cnt[ex];
  }
  __syncthreads();

  if (tid == 0) {
    int s = 0;
    int c8[NEXP];
    for (int ex = 0; ex < NEXP; ++ex) {
      offsets[ex] = s;
      int c = 0;
      for (int ww = 0; ww < 16; ++ww) { lo[ww][ex] = s; s += lc[ww][ex]; c += lc[ww][ex]; }
      counts[ex] = c;
      c8[ex] = c;
    }
    int t = 0;  // round-robin emission: slot p -> expert p%8 while rounds full
    for (int r = 0; r < 128; ++r)
      for (int ex = 0; ex < NEXP; ++ex)
        if (r * 128 < c8[ex]) tlist[t++] = (r << 3) | ex;
    *ntiles = t;
  }
  __syncthreads();

  int cur[NEXP];
#pragma unroll
  for (int ex = 0; ex < NEXP; ++ex) cur[ex] = lo[w][ex];
#pragma unroll
  for (int i = 0; i < 16; ++i) {
    const int item = (w * 16 + i) * 64 + lane;
    const int e = e_i[i];
    int p = 0;
#pragma unroll
    for (int ex = 0; ex < NEXP; ++ex) {
      u64 m = __ballot(e == ex);
      int rank = (int)__popcll(m & ltmask);
      if (e == ex) p = cur[ex] + rank;
      cur[ex] += (int)__popcll(m);
    }
    bucket[p] = item;
    pos[item] = p;
  }
}

// ---------------- grouped GEMM: O[p] = relu(Arow[p] @ W[e]^T), bf16 ----------
// 128x128x64 K-tiles, single-buffered 32KB LDS, XOR-swizzled layout
// (bank-conflict-free), global_load_lds width-16 staging, 16x16x32 bf16 MFMA,
// 4 waves (2x2), 4x4 frags. Grid (MAXTILES, 8): blockIdx.x = tile slot,
// expert = slot%8 (round-robin tlist) -> XCD pinning since gridDim.x%8==0.
//
// __launch_bounds__(256, 5): 5 blocks/CU (5 x 32KB = 160KB LDS exactly).
// Whole grid (1088 blocks <= 1280 slots) co-resident -> 20 waves/CU cover the
// per-K-iter vmcnt drain and the dispatch-round tail disappears.
//
// Swizzle: tile row r holds its 8 16B-chunks permuted by XOR(r&7). Staging
// lane loads global chunk (c&7)^(r&7) into linear LDS chunk c; fragment read
// of global chunk q reads LDS chunk q^(r&7). Each 16-lane ds_read_b128 group
// then covers all 32 banks exactly 2x (2-way = free, m136).
template <int GATHER>
__global__ __launch_bounds__(256, 5)
void moe_gemm_k(const u16* __restrict__ A,
                const u16* __restrict__ W,
                u16* __restrict__ O,
                const int* __restrict__ counts,
                const int* __restrict__ offsets,
                const int* __restrict__ bucket,
                const int* __restrict__ tlist,
                const int* __restrict__ ntiles) {
  if ((int)blockIdx.x >= *ntiles) return;
  const int info = tlist[blockIdx.x];
  const int e    = info & 7;
  const int m0   = (info >> 3) << 7;
  const int cnt  = counts[e];
  const int seg  = offsets[e];
  const int n0   = blockIdx.y << 7;

  __shared__ u16 As[128 * 64];  // 16 KB, row-major [r][64] with chunk swizzle
  __shared__ u16 Bs[128 * 64];  // 16 KB

  const int tid  = threadIdx.x;
  const int lane = tid & 63;
  const int wave = tid >> 6;

  // Staging: tile = 1024 chunks of 16B per matrix; wave issues 4 A + 4 B
  // global_load_lds per K-iter. Global chunk is XOR-swizzled by row.
  int aoff[4], boff[4];
#pragma unroll
  for (int j = 0; j < 4; ++j) {
    const int c   = ((wave << 2) + j) * 64 + lane;  // chunk 0..1023
    const int r   = c >> 3;                         // tile row
    const int c16 = (c & 7) ^ (r & 7);              // swizzled 16B chunk
    int p = seg + m0 + r;
    p = (p < seg + cnt) ? p : (seg + cnt - 1);      // clamp tail rows
    int rowbase;
    if (GATHER) { const int pair = bucket[p]; rowbase = (pair >> 1) * DIM; }
    else        { rowbase = p * DIM; }
    aoff[j] = rowbase + (c16 << 3);
    boff[j] = e * DIM * DIM + (n0 + r) * DIM + (c16 << 3);
  }

  f32x4 acc[4][4] = {};

  const int wm   = (wave >> 1) << 6;
  const int wn   = (wave & 1) << 6;
  const int lr   = lane & 15;
  const int quad = lane >> 4;

  for (int k0 = 0; k0 < DIM; k0 += 64) {
    __syncthreads();  // protect LDS reuse
#pragma unroll
    for (int j = 0; j < 4; ++j) {
      const int instr = (wave << 2) + j;
      gl_lds16(A + aoff[j] + k0, &As[instr << 9]);
      gl_lds16(W + boff[j] + k0, &Bs[instr << 9]);
    }
    __syncthreads();  // drains vmcnt for global_load_lds

#pragma unroll
    for (int kk = 0; kk < 64; kk += 32) {
      const int qb = (kk >> 3) + quad;  // wanted global chunk
      short8 af[4], bf[4];
#pragma unroll
      for (int mi = 0; mi < 4; ++mi) {
        const int r = wm + (mi << 4) + lr;
        af[mi] = *(const short8*)&As[r * 64 + ((qb ^ (r & 7)) << 3)];
      }
#pragma unroll
      for (int ni = 0; ni < 4; ++ni) {
        const int r = wn + (ni << 4) + lr;
        bf[ni] = *(const short8*)&Bs[r * 64 + ((qb ^ (r & 7)) << 3)];
      }
#pragma unroll
      for (int mi = 0; mi < 4; ++mi)
#pragma unroll
        for (int ni = 0; ni < 4; ++ni)
          acc[mi][ni] = __builtin_amdgcn_mfma_f32_16x16x32_bf16(af[mi], bf[ni], acc[mi][ni], 0, 0, 0);
    }
  }

  // Epilogue: relu -> bf16. C/D layout: col = lane&15, row = quad*4 + reg.
  const int pend = seg + cnt;
#pragma unroll
  for (int mi = 0; mi < 4; ++mi) {
#pragma unroll
    for (int ni = 0; ni < 4; ++ni) {
      const int col = n0 + wn + (ni << 4) + lr;
#pragma unroll
      for (int r4 = 0; r4 < 4; ++r4) {
        const int p = seg + m0 + wm + (mi << 4) + (quad << 2) + r4;
        if (p < pend) {
          float v = acc[mi][ni][r4];
          v = v > 0.f ? v : 0.f;
          O[(size_t)p * DIM + col] = f2bf(v);
        }
      }
    }
  }
}

// ---------------- combine: out[t] = w0*y[pos[2t]] + w1*y[pos[2t+1]] ----------
__global__ void combine_k(const u16* __restrict__ y, const int* __restrict__ pos,
                          const float* __restrict__ wts, float* __restrict__ out) {
  const int t    = blockIdx.x * 2 + (threadIdx.x >> 7);
  const int lane = threadIdx.x & 127;
  const int col  = lane * 8;
  const int p0 = pos[2 * t], p1 = pos[2 * t + 1];
  const float w0 = wts[2 * t], w1 = wts[2 * t + 1];
  const short8 a = *(const short8*)(y + (size_t)p0 * DIM + col);
  const short8 b = *(const short8*)(y + (size_t)p1 * DIM + col);
  f32x4 o0, o1;
#pragma unroll
  for (int j = 0; j < 8; ++j) {
    float v = w0 * bf2f((u16)a[j]) + w1 * bf2f((u16)b[j]);
    if (j < 4) o0[j] = v; else o1[j - 4] = v;
  }
  float* op = out + (size_t)t * DIM + col;
  *(f32x4*)op = o0;
  *(f32x4*)(op + 4) = o1;
}

extern "C" void kernel_launch(void* const* d_in, const int* in_sizes, int n_in,
                              void* d_out, int out_size, void* d_ws, size_t ws_size,
                              hipStream_t stream) {
  const float* x   = (const float*)d_in[0];
  const int*   idx = (const int*)d_in[1];
  const float* wts = (const float*)d_in[2];
  const float* W1  = (const float*)d_in[3];
  const float* W2  = (const float*)d_in[4];
  float* out = (float*)d_out;

  char* ws = (char*)d_ws;
  int* counts  = (int*)ws;                       // 8
  int* offsets = (int*)(ws + 32);                // 8
  int* ntiles  = (int*)(ws + 64);                // 1
  int* tlist   = (int*)(ws + 128);               // <=136
  int* bucket  = (int*)(ws + 1024);              // 16384
  int* pos     = (int*)(ws + 1024 + 4 * NPAIR);  // 16384
  const size_t base = 132096;                    // 16B-aligned
  const size_t MB16 = 16ull * 1024 * 1024;
  u16* xb  = (u16*)(ws + base);                  // 16 MB
  u16* w1b = (u16*)(ws + base + MB16);           // 16 MB
  u16* w2b = (u16*)(ws + base + 2 * MB16);       // 16 MB
  u16* h   = (u16*)(ws + base + 3 * MB16);       // 32 MB
  u16* yb  = xb;                                 // 32 MB, aliases xb+w1b (dead)

  // block 0 = sort (starts first, hides under the cast stream)
  prep_k<<<3 * 1024 + 1, 1024, 0, stream>>>(x, W1, W2, xb, w1b, w2b,
                                            idx, counts, offsets, bucket, pos,
                                            tlist, ntiles);

  dim3 gg(MAXTILES, DIM / 128);  // (136, 8): x = tile slot -> XCD = expert
  moe_gemm_k<1><<<gg, 256, 0, stream>>>(xb, w1b, h, counts, offsets, bucket, tlist, ntiles);
  moe_gemm_k<0><<<gg, 256, 0, stream>>>(h, w2b, yb, counts, offsets, bucket, tlist, ntiles);

  combine_k<<<T_TOK / 2, 256, 0, stream>>>(yb, pos, wts, out);
}

// Round 2
// 243.887 us; speedup vs baseline: 1.3422x; 1.3422x over previous
//
#include <hip/hip_runtime.h>

typedef unsigned short u16;
typedef unsigned int   u32;
typedef unsigned long long u64;
typedef __attribute__((ext_vector_type(8))) short short8;
typedef __attribute__((ext_vector_type(4))) float f32x4;

#define T_TOK 8192
#define DIM   1024
#define NEXP  8
#define NPAIR (T_TOK * 2)   // 16384 token-expert pairs
#define MAXTILES 136        // sum ceil(cnt_e/128) <= 128 + 7; 136 % 8 == 0

__device__ __forceinline__ u16 f2bf(float f) {
  u32 u = __builtin_bit_cast(u32, f);
  u32 r = (u + 0x7fffu + ((u >> 16) & 1u)) >> 16;  // RNE
  return (u16)r;
}
__device__ __forceinline__ float bf2f(u16 b) {
  return __builtin_bit_cast(float, ((u32)b) << 16);
}

__device__ __forceinline__ void gl_lds16(const u16* g, u16* l) {
  __builtin_amdgcn_global_load_lds(
      (const __attribute__((address_space(1))) u32*)g,
      (__attribute__((address_space(3))) u32*)l,
      16, 0, 0);
}

// ---------------- fused prep: cast x/W1/W2 to bf16 + pair sort ---------------
// Block 0 runs the single-block ballot sort; blocks 1..3072 stream the
// fp32->bf16 cast (1024 thr x 8 elems). The ~10us serial sort hides under the
// BW-bound cast (measured R1: saved ~40us of non-GEMM time vs separate launch).
__global__ void prep_k(const float* __restrict__ x, const float* __restrict__ W1,
                       const float* __restrict__ W2,
                       u16* __restrict__ xb, u16* __restrict__ w1b, u16* __restrict__ w2b,
                       const int* __restrict__ idx,
                       int* __restrict__ counts, int* __restrict__ offsets,
                       int* __restrict__ bucket, int* __restrict__ pos,
                       int* __restrict__ tlist, int* __restrict__ ntiles) {
  __shared__ int lc[16][NEXP];
  __shared__ int lo[16][NEXP];

  if (blockIdx.x != 0) {
    // ---- cast path: 3072 blocks x 1024 threads x 8 elems = 3 x 8388608 ----
    const int g = ((int)(blockIdx.x - 1) * 1024 + (int)threadIdx.x) * 8;
    const int region = g >> 23;                      // 8388608 elems per region
    const int i = g & 0x7fffff;
    const float* s = (region == 0) ? x : (region == 1) ? W1 : W2;
    u16* d = (region == 0) ? xb : (region == 1) ? w1b : w2b;
    f32x4 a = *(const f32x4*)(s + i);
    f32x4 b = *(const f32x4*)(s + i + 4);
    short8 o;
    o[0] = (short)f2bf(a[0]); o[1] = (short)f2bf(a[1]);
    o[2] = (short)f2bf(a[2]); o[3] = (short)f2bf(a[3]);
    o[4] = (short)f2bf(b[0]); o[5] = (short)f2bf(b[1]);
    o[6] = (short)f2bf(b[2]); o[7] = (short)f2bf(b[3]);
    *(short8*)(d + i) = o;
    return;
  }

  // ---- sort path: bucket pairs by expert, ballot-based, no atomics ----
  // Emits tlist ROUND-ROBIN over experts so tile-slot p has expert p%8,
  // enabling the expert->XCD L2-locality swizzle in the GEMM.
  const int tid  = threadIdx.x;
  const int w    = tid >> 6;
  const int lane = tid & 63;
  const u64 ltmask = (lane == 63) ? 0x7fffffffffffffffull : ((1ull << lane) - 1);

  int e_i[16];
#pragma unroll
  for (int i = 0; i < 16; ++i) e_i[i] = idx[(w * 16 + i) * 64 + lane];

  int cnt[NEXP] = {};
#pragma unroll
  for (int i = 0; i < 16; ++i) {
#pragma unroll
    for (int ex = 0; ex < NEXP; ++ex) {
      u64 m = __ballot(e_i[i] == ex);
      cnt[ex] += (int)__popcll(m);
    }
  }
  if (lane == 0) {
#pragma unroll
    for (int ex = 0; ex < NEXP; ++ex) lc[w][ex] = cnt[ex];
  }
  __syncthreads();

  if (tid == 0) {
    int s = 0;
    int c8[NEXP];
    for (int ex = 0; ex < NEXP; ++ex) {
      offsets[ex] = s;
      int c = 0;
      for (int ww = 0; ww < 16; ++ww) { lo[ww][ex] = s; s += lc[ww][ex]; c += lc[ww][ex]; }
      counts[ex] = c;
      c8[ex] = c;
    }
    int t = 0;  // round-robin emission: slot p -> expert p%8 while rounds full
    for (int r = 0; r < 128; ++r)
      for (int ex = 0; ex < NEXP; ++ex)
        if (r * 128 < c8[ex]) tlist[t++] = (r << 3) | ex;
    *ntiles = t;
  }
  __syncthreads();

  int cur[NEXP];
#pragma unroll
  for (int ex = 0; ex < NEXP; ++ex) cur[ex] = lo[w][ex];
#pragma unroll
  for (int i = 0; i < 16; ++i) {
    const int item = (w * 16 + i) * 64 + lane;
    const int e = e_i[i];
    int p = 0;
#pragma unroll
    for (int ex = 0; ex < NEXP; ++ex) {
      u64 m = __ballot(e == ex);
      int rank = (int)__popcll(m & ltmask);
      if (e == ex) p = cur[ex] + rank;
      cur[ex] += (int)__popcll(m);
    }
    bucket[p] = item;
    pos[item] = p;
  }
}

// ---------------- grouped GEMM: O[p] = relu(Arow[p] @ W[e]^T), bf16 ----------
// 128x128x64 K-tiles, single-buffered 32KB LDS, XOR-swizzled layout
// (bank-conflict-free), global_load_lds width-16 staging, 16x16x32 bf16 MFMA,
// 4 waves (2x2), 4x4 frags. Grid (MAXTILES, 8): blockIdx.x = tile slot,
// expert = slot%8 (round-robin tlist) -> XCD pinning since gridDim.x%8==0.
//
// __launch_bounds__(256, 4): 4 blocks/CU = 1024 slots, so 1088 blocks pack at
// 94% (vs 71% at 3/CU). Register check: ~60 VGPR + 64 AGPR = 124 <= 128/wave
// budget at 4 waves/SIMD -> no spill. (R1 lesson: 5/CU forces ~102-reg budget
// -> 15MB of scratch spill per dispatch, 2x slowdown. Do NOT raise past 4.)
//
// Swizzle: tile row r holds its 8 16B-chunks permuted by XOR(r&7). Staging
// lane loads global chunk (c&7)^(r&7) into linear LDS chunk c; fragment read
// of global chunk q reads LDS chunk q^(r&7). Each 16-lane ds_read_b128 group
// then covers all 32 banks exactly 2x (2-way = free, m136).
template <int GATHER>
__global__ __launch_bounds__(256, 4)
void moe_gemm_k(const u16* __restrict__ A,
                const u16* __restrict__ W,
                u16* __restrict__ O,
                const int* __restrict__ counts,
                const int* __restrict__ offsets,
                const int* __restrict__ bucket,
                const int* __restrict__ tlist,
                const int* __restrict__ ntiles) {
  if ((int)blockIdx.x >= *ntiles) return;
  const int info = tlist[blockIdx.x];
  const int e    = info & 7;
  const int m0   = (info >> 3) << 7;
  const int cnt  = counts[e];
  const int seg  = offsets[e];
  const int n0   = blockIdx.y << 7;

  __shared__ u16 As[128 * 64];  // 16 KB, row-major [r][64] with chunk swizzle
  __shared__ u16 Bs[128 * 64];  // 16 KB

  const int tid  = threadIdx.x;
  const int lane = tid & 63;
  const int wave = tid >> 6;

  // Staging: tile = 1024 chunks of 16B per matrix; wave issues 4 A + 4 B
  // global_load_lds per K-iter. Global chunk is XOR-swizzled by row.
  int aoff[4], boff[4];
#pragma unroll
  for (int j = 0; j < 4; ++j) {
    const int c   = ((wave << 2) + j) * 64 + lane;  // chunk 0..1023
    const int r   = c >> 3;                         // tile row
    const int c16 = (c & 7) ^ (r & 7);              // swizzled 16B chunk
    int p = seg + m0 + r;
    p = (p < seg + cnt) ? p : (seg + cnt - 1);      // clamp tail rows
    int rowbase;
    if (GATHER) { const int pair = bucket[p]; rowbase = (pair >> 1) * DIM; }
    else        { rowbase = p * DIM; }
    aoff[j] = rowbase + (c16 << 3);
    boff[j] = e * DIM * DIM + (n0 + r) * DIM + (c16 << 3);
  }

  f32x4 acc[4][4] = {};

  const int wm   = (wave >> 1) << 6;
  const int wn   = (wave & 1) << 6;
  const int lr   = lane & 15;
  const int quad = lane >> 4;

  for (int k0 = 0; k0 < DIM; k0 += 64) {
    __syncthreads();  // protect LDS reuse
#pragma unroll
    for (int j = 0; j < 4; ++j) {
      const int instr = (wave << 2) + j;
      gl_lds16(A + aoff[j] + k0, &As[instr << 9]);
      gl_lds16(W + boff[j] + k0, &Bs[instr << 9]);
    }
    __syncthreads();  // drains vmcnt for global_load_lds

#pragma unroll
    for (int kk = 0; kk < 64; kk += 32) {
      const int qb = (kk >> 3) + quad;  // wanted global chunk
      short8 af[4], bf[4];
#pragma unroll
      for (int mi = 0; mi < 4; ++mi) {
        const int r = wm + (mi << 4) + lr;
        af[mi] = *(const short8*)&As[r * 64 + ((qb ^ (r & 7)) << 3)];
      }
#pragma unroll
      for (int ni = 0; ni < 4; ++ni) {
        const int r = wn + (ni << 4) + lr;
        bf[ni] = *(const short8*)&Bs[r * 64 + ((qb ^ (r & 7)) << 3)];
      }
#pragma unroll
      for (int mi = 0; mi < 4; ++mi)
#pragma unroll
        for (int ni = 0; ni < 4; ++ni)
          acc[mi][ni] = __builtin_amdgcn_mfma_f32_16x16x32_bf16(af[mi], bf[ni], acc[mi][ni], 0, 0, 0);
    }
  }

  // Epilogue: relu -> bf16. C/D layout: col = lane&15, row = quad*4 + reg.
  const int pend = seg + cnt;
#pragma unroll
  for (int mi = 0; mi < 4; ++mi) {
#pragma unroll
    for (int ni = 0; ni < 4; ++ni) {
      const int col = n0 + wn + (ni << 4) + lr;
#pragma unroll
      for (int r4 = 0; r4 < 4; ++r4) {
        const int p = seg + m0 + wm + (mi << 4) + (quad << 2) + r4;
        if (p < pend) {
          float v = acc[mi][ni][r4];
          v = v > 0.f ? v : 0.f;
          O[(size_t)p * DIM + col] = f2bf(v);
        }
      }
    }
  }
}

// ---------------- combine: out[t] = w0*y[pos[2t]] + w1*y[pos[2t+1]] ----------
__global__ void combine_k(const u16* __restrict__ y, const int* __restrict__ pos,
                          const float* __restrict__ wts, float* __restrict__ out) {
  const int t    = blockIdx.x * 2 + (threadIdx.x >> 7);
  const int lane = threadIdx.x & 127;
  const int col  = lane * 8;
  const int p0 = pos[2 * t], p1 = pos[2 * t + 1];
  const float w0 = wts[2 * t], w1 = wts[2 * t + 1];
  const short8 a = *(const short8*)(y + (size_t)p0 * DIM + col);
  const short8 b = *(const short8*)(y + (size_t)p1 * DIM + col);
  f32x4 o0, o1;
#pragma unroll
  for (int j = 0; j < 8; ++j) {
    float v = w0 * bf2f((u16)a[j]) + w1 * bf2f((u16)b[j]);
    if (j < 4) o0[j] = v; else o1[j - 4] = v;
  }
  float* op = out + (size_t)t * DIM + col;
  *(f32x4*)op = o0;
  *(f32x4*)(op + 4) = o1;
}

extern "C" void kernel_launch(void* const* d_in, const int* in_sizes, int n_in,
                              void* d_out, int out_size, void* d_ws, size_t ws_size,
                              hipStream_t stream) {
  const float* x   = (const float*)d_in[0];
  const int*   idx = (const int*)d_in[1];
  const float* wts = (const float*)d_in[2];
  const float* W1  = (const float*)d_in[3];
  const float* W2  = (const float*)d_in[4];
  float* out = (float*)d_out;

  char* ws = (char*)d_ws;
  int* counts  = (int*)ws;                       // 8
  int* offsets = (int*)(ws + 32);                // 8
  int* ntiles  = (int*)(ws + 64);                // 1
  int* tlist   = (int*)(ws + 128);               // <=136
  int* bucket  = (int*)(ws + 1024);              // 16384
  int* pos     = (int*)(ws + 1024 + 4 * NPAIR);  // 16384
  const size_t base = 132096;                    // 16B-aligned
  const size_t MB16 = 16ull * 1024 * 1024;
  u16* xb  = (u16*)(ws + base);                  // 16 MB
  u16* w1b = (u16*)(ws + base + MB16);           // 16 MB
  u16* w2b = (u16*)(ws + base + 2 * MB16);       // 16 MB
  u16* h   = (u16*)(ws + base + 3 * MB16);       // 32 MB
  u16* yb  = xb;                                 // 32 MB, aliases xb+w1b (dead)

  // block 0 = sort (starts first, hides under the cast stream)
  prep_k<<<3 * 1024 + 1, 1024, 0, stream>>>(x, W1, W2, xb, w1b, w2b,
                                            idx, counts, offsets, bucket, pos,
                                            tlist, ntiles);

  dim3 gg(MAXTILES, DIM / 128);  // (136, 8): x = tile slot -> XCD = expert
  moe_gemm_k<1><<<gg, 256, 0, stream>>>(xb, w1b, h, counts, offsets, bucket, tlist, ntiles);
  moe_gemm_k<0><<<gg, 256, 0, stream>>>(h, w2b, yb, counts, offsets, bucket, tlist, ntiles);

  combine_k<<<T_TOK / 2, 256, 0, stream>>>(yb, pos, wts, out);
}